// Round 2
// baseline (2566.761 us; speedup 1.0000x reference)
//
#include <hip/hip_runtime.h>
#include <hip/hip_bf16.h>

#define R_REL 2016
#define MROWS 16384
#define HDIM  1024
#define EDIM  768
#define FFEAT 64
#define TOPK  28

// C[M,N] = scale * (A[M,K] @ B[N,K]^T) + bias[N]
// Both A and B row-major with K contiguous (NT GEMM). K % 16 == 0, K-rows 16B aligned.
__global__ __launch_bounds__(256) void gemm_nt_f32(
    const float* __restrict__ A, const float* __restrict__ B,
    const float* __restrict__ bias, float* __restrict__ C,
    int M, int N, int K, float scale)
{
  constexpr int BM = 128, BN = 128, BK = 16;
  __shared__ float As[BK][BM + 1];
  __shared__ float Bs[BK][BN + 1];
  const int tid = threadIdx.x;
  const int tx = tid & 15, ty = tid >> 4;
  const int r0 = blockIdx.y * BM, c0 = blockIdx.x * BN;

  float acc[8][8];
#pragma unroll
  for (int i = 0; i < 8; ++i)
#pragma unroll
    for (int j = 0; j < 8; ++j) acc[i][j] = 0.f;

  for (int k0 = 0; k0 < K; k0 += BK) {
#pragma unroll
    for (int it = 0; it < 2; ++it) {
      int l = tid + it * 256;        // float4 slot 0..511
      int row = l >> 2;              // 0..127
      int kv = l & 3;
      int gr = r0 + row; gr = (gr < M) ? gr : (M - 1);
      const float4 f = *reinterpret_cast<const float4*>(A + (size_t)gr * K + k0 + kv * 4);
      As[kv * 4 + 0][row] = f.x; As[kv * 4 + 1][row] = f.y;
      As[kv * 4 + 2][row] = f.z; As[kv * 4 + 3][row] = f.w;
    }
#pragma unroll
    for (int it = 0; it < 2; ++it) {
      int l = tid + it * 256;
      int row = l >> 2;
      int kv = l & 3;
      int gc = c0 + row; gc = (gc < N) ? gc : (N - 1);
      const float4 f = *reinterpret_cast<const float4*>(B + (size_t)gc * K + k0 + kv * 4);
      Bs[kv * 4 + 0][row] = f.x; Bs[kv * 4 + 1][row] = f.y;
      Bs[kv * 4 + 2][row] = f.z; Bs[kv * 4 + 3][row] = f.w;
    }
    __syncthreads();
#pragma unroll
    for (int kk = 0; kk < BK; ++kk) {
      float a[8], b[8];
#pragma unroll
      for (int i = 0; i < 4; ++i) { a[i] = As[kk][ty * 4 + i]; a[i + 4] = As[kk][64 + ty * 4 + i]; }
#pragma unroll
      for (int j = 0; j < 4; ++j) { b[j] = Bs[kk][tx * 4 + j]; b[j + 4] = Bs[kk][64 + tx * 4 + j]; }
#pragma unroll
      for (int i = 0; i < 8; ++i)
#pragma unroll
        for (int j = 0; j < 8; ++j)
          acc[i][j] = fmaf(a[i], b[j], acc[i][j]);
    }
    __syncthreads();
  }
#pragma unroll
  for (int i = 0; i < 8; ++i) {
    int r = r0 + ((i < 4) ? (ty * 4 + i) : (64 + ty * 4 + (i - 4)));
    if (r >= M) continue;
#pragma unroll
    for (int j = 0; j < 8; ++j) {
      int c = c0 + ((j < 4) ? (tx * 4 + j) : (64 + tx * 4 + (j - 4)));
      if (c >= N) continue;
      float v = acc[i][j] * scale;
      if (bias) v += bias[c];
      C[(size_t)r * N + c] = v;
    }
  }
}

// Detect how the bool surviving_mask was materialized: 0=int32, 1=uint8, 2=f32.
// f32 {0.,1.}: nonzero words are exactly 0x3F800000. int32 {0,1}: words in {0,1}.
// uint8 {0,1} bytes viewed as words: values like 0x00010001 (>1, never 0x3F800000).
__global__ void detect_mask_kind(const unsigned int* __restrict__ m, int* __restrict__ flag) {
  if (threadIdx.x == 0 && blockIdx.x == 0) {
    int kind = 0;
    bool saw_gt1 = false;
    for (int i = 0; i < 256; ++i) {
      unsigned w = m[i];
      if (w == 0x3F800000u) { kind = 2; saw_gt1 = false; break; }
      if (w > 1u) saw_gt1 = true;
    }
    if (kind != 2 && saw_gt1) kind = 1;
    *flag = kind;
  }
}

// Canonical per-row 64-bit feature bitmask.
__global__ __launch_bounds__(256) void build_fbits(
    const void* __restrict__ mask, const int* __restrict__ kind,
    unsigned long long* __restrict__ fbits)
{
  const int gm = blockIdx.x * 4 + (threadIdx.x >> 6);
  const int lane = threadIdx.x & 63;
  const int k = *kind;
  const size_t e = (size_t)gm * FFEAT + lane;
  bool on;
  if (k == 0)      on = ((const int*)mask)[e] != 0;
  else if (k == 1) on = ((const unsigned char*)mask)[e] != 0;
  else             on = ((const float*)mask)[e] != 0.f;
  const unsigned long long b = __ballot(on);
  if (lane == 0) fbits[gm] = b;
}

// One wave per (b,t) row: 28x shuffle-argmax (ties -> lowest index, matching
// jax.lax.top_k), then softmax over selected.
__global__ __launch_bounds__(64) void topk_softmax_k(
    const float* __restrict__ S,                    // [mc][R_REL] score chunk
    const unsigned long long* __restrict__ fbits,   // [MROWS]
    const int* __restrict__ f_i, const int* __restrict__ f_j,
    int* __restrict__ topidx, float* __restrict__ topw, // [MROWS][TOPK]
    int row0)
{
  const int lr = blockIdx.x;
  const int gm = row0 + lr;
  const int lane = threadIdx.x;
  const unsigned long long fb = fbits[gm];

  float val[32];
#pragma unroll
  for (int j = 0; j < 32; ++j) {
    int rr = lane + j * 64;
    float v = -INFINITY;
    if (rr < R_REL) {
      int fi = f_i[rr], fj = f_j[rr];
      if (((fb >> fi) & 1ULL) && ((fb >> fj) & 1ULL))
        v = S[(size_t)lr * R_REL + rr];
    }
    val[j] = v;
  }

  float myv = 0.f; int myi = 0;
  float m0 = 0.f;
  int nsel = 0;
  for (int it = 0; it < TOPK; ++it) {
    float bv = -INFINITY; int bi = 0x7fffffff;
#pragma unroll
    for (int j = 0; j < 32; ++j) {
      if (val[j] > bv) { bv = val[j]; bi = lane + j * 64; }  // ascending rr: strict > keeps lowest idx
    }
#pragma unroll
    for (int off = 32; off; off >>= 1) {
      float ov = __shfl_xor(bv, off);
      int oi = __shfl_xor(bi, off);
      if (ov > bv || (ov == bv && oi < bi)) { bv = ov; bi = oi; }
    }
    if (bv == -INFINITY) break;
    if (it == 0) m0 = bv;
    if (lane == it) { myv = bv; myi = bi; }
    nsel = it + 1;
    const int cj = bi >> 6, cl = bi & 63;
#pragma unroll
    for (int j = 0; j < 32; ++j)     // predicated clear -> stays in VGPRs
      if (j == cj && lane == cl) val[j] = -INFINITY;
  }

  float e = (lane < nsel) ? expf(myv - m0) : 0.f;
  float z = e;
#pragma unroll
  for (int off = 32; off; off >>= 1) z += __shfl_xor(z, off);
  if (lane < TOPK) {
    float w = (lane < nsel) ? (e / z) : 0.f;
    topw[(size_t)gm * TOPK + lane] = w;
    topidx[(size_t)gm * TOPK + lane] = (lane < nsel) ? myi : 0;
  }
}

// out[gm,:] = sum_i w_i * V[idx_i,:]   (28 sparse terms; zero-weight rows -> 0)
__global__ __launch_bounds__(256) void out_gather(
    const int* __restrict__ topidx, const float* __restrict__ topw,
    const float* __restrict__ V, float* __restrict__ out)
{
  const int gm = blockIdx.x;
  const int tid = threadIdx.x;
  __shared__ float w[TOPK];
  __shared__ int   id[TOPK];
  if (tid < TOPK) {
    w[tid] = topw[(size_t)gm * TOPK + tid];
    id[tid] = topidx[(size_t)gm * TOPK + tid];
  }
  __syncthreads();
  float4 acc = make_float4(0.f, 0.f, 0.f, 0.f);
#pragma unroll 4
  for (int i = 0; i < TOPK; ++i) {
    const float wi = w[i];
    const float4 v = *reinterpret_cast<const float4*>(V + (size_t)id[i] * HDIM + tid * 4);
    acc.x = fmaf(wi, v.x, acc.x);
    acc.y = fmaf(wi, v.y, acc.y);
    acc.z = fmaf(wi, v.z, acc.z);
    acc.w = fmaf(wi, v.w, acc.w);
  }
  *reinterpret_cast<float4*>(out + (size_t)gm * HDIM + tid * 4) = acc;
}

extern "C" void kernel_launch(void* const* d_in, const int* in_sizes, int n_in,
                              void* d_out, int out_size, void* d_ws, size_t ws_size,
                              hipStream_t stream) {
  const float* qh  = (const float*)d_in[0];
  const void*  mask = d_in[1];
  const float* rel = (const float*)d_in[2];
  const int* f_i = (const int*)d_in[3];
  const int* f_j = (const int*)d_in[4];
  const float* Wt = (const float*)d_in[5]; const float* bt = (const float*)d_in[6];
  const float* Wq = (const float*)d_in[7]; const float* bq = (const float*)d_in[8];
  const float* Wk = (const float*)d_in[9]; const float* bk = (const float*)d_in[10];
  const float* Wv = (const float*)d_in[11]; const float* bv = (const float*)d_in[12];
  float* out = (float*)d_out;

  // ws layout: ta[R*H] f32 | Km[R*H] | Vm[R*H] | fbits[M] u64 | kindflag | tidx[M*28] i32 | tw[M*28] f32 | sc[mc*R]
  float* ta = (float*)d_ws;
  float* Km = ta + (size_t)R_REL * HDIM;
  float* Vm = Km + (size_t)R_REL * HDIM;
  unsigned long long* fbits = (unsigned long long*)(Vm + (size_t)R_REL * HDIM);
  int* kindflag = (int*)(fbits + MROWS);
  int* tidx = kindflag + 4;  // keep 16B alignment
  float* tw = (float*)(tidx + (size_t)MROWS * TOPK);
  float* sc = tw + (size_t)MROWS * TOPK;
  // Q lives in d_out (exactly MROWS*HDIM floats), overwritten by out_gather at the end.
  float* Q = out;

  const size_t fixed = ((size_t)R_REL * HDIM * 3 + (size_t)MROWS * TOPK * 2 + 4) * 4
                     + (size_t)MROWS * 8;
  const size_t avail = (ws_size > fixed) ? (ws_size - fixed) : 0;
  int mc = MROWS;
  while (mc > 512 && (size_t)mc * R_REL * 4 > avail) mc >>= 1;

  const dim3 blk(256);
  auto grid_of = [](int m, int n) { return dim3((unsigned)((n + 127) / 128), (unsigned)((m + 127) / 128)); };

  detect_mask_kind<<<1, 64, 0, stream>>>((const unsigned int*)mask, kindflag);
  build_fbits<<<dim3(MROWS / 4), blk, 0, stream>>>(mask, kindflag, fbits);

  // ta = rel @ Wt^T + bt
  gemm_nt_f32<<<grid_of(R_REL, HDIM), blk, 0, stream>>>(rel, Wt, bt, ta, R_REL, HDIM, EDIM, 1.f);
  // Km = ta @ Wk^T + bk ; Vm = ta @ Wv^T + bv
  gemm_nt_f32<<<grid_of(R_REL, HDIM), blk, 0, stream>>>(ta, Wk, bk, Km, R_REL, HDIM, HDIM, 1.f);
  gemm_nt_f32<<<grid_of(R_REL, HDIM), blk, 0, stream>>>(ta, Wv, bv, Vm, R_REL, HDIM, HDIM, 1.f);
  // Q = qh @ Wq^T + bq   (into d_out)
  gemm_nt_f32<<<grid_of(MROWS, HDIM), blk, 0, stream>>>(qh, Wq, bq, Q, MROWS, HDIM, HDIM, 1.f);

  for (int r0 = 0; r0 < MROWS; r0 += mc) {
    const int m = (MROWS - r0 < mc) ? (MROWS - r0) : mc;
    // scores chunk = (Qchunk @ Km^T) / 32   (exact pow2 scale)
    gemm_nt_f32<<<grid_of(m, R_REL), blk, 0, stream>>>(Q + (size_t)r0 * HDIM, Km, nullptr, sc, m, R_REL, HDIM, 0.03125f);
    topk_softmax_k<<<dim3((unsigned)m), dim3(64), 0, stream>>>(sc, fbits, f_i, f_j, tidx, tw, r0);
  }

  out_gather<<<dim3((unsigned)MROWS), blk, 0, stream>>>(tidx, tw, Vm, out);
}

// Round 3
// 1037.583 us; speedup vs baseline: 2.4738x; 2.4738x over previous
//
#include <hip/hip_runtime.h>
#include <hip/hip_bf16.h>

#define R_REL 2016
#define MROWS 16384
#define HDIM  1024
#define EDIM  768
#define FFEAT 64
#define TOPK  28
#define NCAND 32
#define NPAD  2048

typedef unsigned short u16;
typedef __attribute__((ext_vector_type(8))) short short8;
typedef __attribute__((ext_vector_type(4))) float f32x4;

__device__ inline float bf2f(u16 u) {
  unsigned x = ((unsigned)u) << 16; float f;
  __builtin_memcpy(&f, &x, 4); return f;
}
__device__ inline u16 f2bf(float f) {
  __hip_bfloat16 h = __float2bfloat16(f);
  u16 u; __builtin_memcpy(&u, &h, 2); return u;
}
__device__ inline void gl2lds16(const void* g, void* l) {
  __builtin_amdgcn_global_load_lds((const __attribute__((address_space(1))) unsigned int*)g,
                                   (__attribute__((address_space(3))) unsigned int*)l, 16, 0, 0);
}

// ---------------- exact f32 NT GEMM (z-batched: blockIdx.z picks B/bias/C) ----------------
// C[M,N] = scale*(A@B^T) + bias. float4 LDS reads; +4 pad keeps 16B align, 2-way max conflict.
__global__ __launch_bounds__(256) void gemm_nt_f32(
    const float* __restrict__ A,
    const float* __restrict__ B0, const float* __restrict__ bias0, float* __restrict__ C0,
    const float* __restrict__ B1, const float* __restrict__ bias1, float* __restrict__ C1,
    int M, int N, int K, float scale)
{
  constexpr int BM = 128, BN = 128, BK = 16;
  __shared__ float As[BK][BM + 4];
  __shared__ float Bs[BK][BN + 4];
  const float* B = blockIdx.z ? B1 : B0;
  const float* bias = blockIdx.z ? bias1 : bias0;
  float* C = blockIdx.z ? C1 : C0;
  const int tid = threadIdx.x;
  const int tx = tid & 15, ty = tid >> 4;
  const int r0 = blockIdx.y * BM, c0 = blockIdx.x * BN;

  float acc[8][8];
#pragma unroll
  for (int i = 0; i < 8; ++i)
#pragma unroll
    for (int j = 0; j < 8; ++j) acc[i][j] = 0.f;

  for (int k0 = 0; k0 < K; k0 += BK) {
#pragma unroll
    for (int it = 0; it < 2; ++it) {
      int l = tid + it * 256;
      int row = l >> 2, kv = l & 3;
      int gr = r0 + row; gr = (gr < M) ? gr : (M - 1);
      const float4 f = *reinterpret_cast<const float4*>(A + (size_t)gr * K + k0 + kv * 4);
      As[kv * 4 + 0][row] = f.x; As[kv * 4 + 1][row] = f.y;
      As[kv * 4 + 2][row] = f.z; As[kv * 4 + 3][row] = f.w;
    }
#pragma unroll
    for (int it = 0; it < 2; ++it) {
      int l = tid + it * 256;
      int row = l >> 2, kv = l & 3;
      int gc = c0 + row; gc = (gc < N) ? gc : (N - 1);
      const float4 f = *reinterpret_cast<const float4*>(B + (size_t)gc * K + k0 + kv * 4);
      Bs[kv * 4 + 0][row] = f.x; Bs[kv * 4 + 1][row] = f.y;
      Bs[kv * 4 + 2][row] = f.z; Bs[kv * 4 + 3][row] = f.w;
    }
    __syncthreads();
#pragma unroll
    for (int kk = 0; kk < BK; ++kk) {
      const float4 a0 = *reinterpret_cast<const float4*>(&As[kk][ty * 4]);
      const float4 a1 = *reinterpret_cast<const float4*>(&As[kk][64 + ty * 4]);
      const float4 b0 = *reinterpret_cast<const float4*>(&Bs[kk][tx * 4]);
      const float4 b1 = *reinterpret_cast<const float4*>(&Bs[kk][64 + tx * 4]);
      const float a[8] = {a0.x, a0.y, a0.z, a0.w, a1.x, a1.y, a1.z, a1.w};
      const float b[8] = {b0.x, b0.y, b0.z, b0.w, b1.x, b1.y, b1.z, b1.w};
#pragma unroll
      for (int i = 0; i < 8; ++i)
#pragma unroll
        for (int j = 0; j < 8; ++j)
          acc[i][j] = fmaf(a[i], b[j], acc[i][j]);
    }
    __syncthreads();
  }
#pragma unroll
  for (int i = 0; i < 8; ++i) {
    int r = r0 + ((i < 4) ? (ty * 4 + i) : (64 + ty * 4 + (i - 4)));
    if (r >= M) continue;
#pragma unroll
    for (int j = 0; j < 8; ++j) {
      int c = c0 + ((j < 4) ? (tx * 4 + j) : (64 + tx * 4 + (j - 4)));
      if (c >= N) continue;
      float v = acc[i][j] * scale;
      if (bias) v += bias[c];
      C[(size_t)r * N + c] = v;
    }
  }
}

// ---------------- bf16 MFMA NT GEMM: St[M][NPAD](bf16) = (qhb@W2b^T + cvec)*scale --------
// 128x128 tile, BK=32, 4 waves, 16x16x32 mfma, global_load_lds w/ XOR-swizzled source.
__global__ __launch_bounds__(256) void gemm_bf16_scores(
    const u16* __restrict__ A, const u16* __restrict__ B,
    const float* __restrict__ cvec, u16* __restrict__ St, int K)
{
  __shared__ u16 ldsA[128 * 32];
  __shared__ u16 ldsB[128 * 32];
  const int tid = threadIdx.x;
  const int wave = tid >> 6, lane = tid & 63;
  const int wr = wave >> 1, wc = wave & 1;
  const int row0 = blockIdx.y * 128, col0 = blockIdx.x * 128;

  f32x4 acc[4][4];
#pragma unroll
  for (int m = 0; m < 4; ++m)
#pragma unroll
    for (int n = 0; n < 4; ++n) acc[m][n] = (f32x4){0.f, 0.f, 0.f, 0.f};

  const int srow = (lane >> 2);           // row within 16-row stripe
  const int sslot = lane & 3;             // physical 16B slot

  for (int k0 = 0; k0 < K; k0 += 32) {
#pragma unroll
    for (int j = 0; j < 2; ++j) {
      const int row = (wave * 2 + j) * 16 + srow;
      const int s = (row >> 1) & 3;
      const int kg = sslot ^ s;           // inverse-swizzled source col-block
      gl2lds16((const char*)A + ((size_t)(row0 + row) * K + k0 + kg * 8) * 2,
               (char*)ldsA + (size_t)(wave * 2 + j) * 1024);
      gl2lds16((const char*)B + ((size_t)(col0 + row) * K + k0 + kg * 8) * 2,
               (char*)ldsB + (size_t)(wave * 2 + j) * 1024);
    }
    __syncthreads();
    const int r15 = lane & 15, kq = lane >> 4;
    short8 a[4], b[4];
#pragma unroll
    for (int m = 0; m < 4; ++m) {
      const int rowL = wr * 64 + m * 16 + r15;
      const int slot = kq ^ ((rowL >> 1) & 3);
      a[m] = *reinterpret_cast<const short8*>(&ldsA[rowL * 32 + slot * 8]);
    }
#pragma unroll
    for (int n = 0; n < 4; ++n) {
      const int colL = wc * 64 + n * 16 + r15;
      const int slot = kq ^ ((colL >> 1) & 3);
      b[n] = *reinterpret_cast<const short8*>(&ldsB[colL * 32 + slot * 8]);
    }
#pragma unroll
    for (int m = 0; m < 4; ++m)
#pragma unroll
      for (int n = 0; n < 4; ++n)
        acc[m][n] = __builtin_amdgcn_mfma_f32_16x16x32_bf16(a[m], b[n], acc[m][n], 0, 0, 0);
    __syncthreads();
  }
  const int r15 = lane & 15, quad = lane >> 4;
#pragma unroll
  for (int m = 0; m < 4; ++m)
#pragma unroll
    for (int n = 0; n < 4; ++n) {
      const int cg = col0 + wc * 64 + n * 16 + r15;
      if (cg >= R_REL) continue;
      const float cv = cvec[cg];
#pragma unroll
      for (int reg = 0; reg < 4; ++reg) {
        const int rg = row0 + wr * 64 + m * 16 + quad * 4 + reg;
        St[(size_t)rg * NPAD + cg] = f2bf((acc[m][n][reg] + cv) * 0.03125f);
      }
    }
}

// ---------------- small helpers ----------------
__global__ void detect_mask_kind(const unsigned int* __restrict__ m, int* __restrict__ flag) {
  if (threadIdx.x == 0 && blockIdx.x == 0) {
    int kind = 0; bool saw_gt1 = false;
    for (int i = 0; i < 256; ++i) {
      unsigned w = m[i];
      if (w == 0x3F800000u) { kind = 2; saw_gt1 = false; break; }
      if (w > 1u) saw_gt1 = true;
    }
    if (kind != 2 && saw_gt1) kind = 1;
    *flag = kind;
  }
}

__global__ __launch_bounds__(256) void build_fbits(
    const void* __restrict__ mask, const int* __restrict__ kind,
    unsigned long long* __restrict__ fbits)
{
  const int gm = blockIdx.x * 4 + (threadIdx.x >> 6);
  const int lane = threadIdx.x & 63;
  const int k = *kind;
  const size_t e = (size_t)gm * FFEAT + lane;
  bool on;
  if (k == 0)      on = ((const int*)mask)[e] != 0;
  else if (k == 1) on = ((const unsigned char*)mask)[e] != 0;
  else             on = ((const float*)mask)[e] != 0.f;
  const unsigned long long b = __ballot(on);
  if (lane == 0) fbits[gm] = b;
}

__global__ __launch_bounds__(256) void transpose1024(const float* __restrict__ in, float* __restrict__ out) {
  __shared__ float t[32][33];
  const int x = threadIdx.x & 31, y = threadIdx.x >> 5;
  const int bx = blockIdx.x, by = blockIdx.y;
#pragma unroll
  for (int yy = 0; yy < 4; ++yy)
    t[y + yy * 8][x] = in[(size_t)(by * 32 + y + yy * 8) * 1024 + bx * 32 + x];
  __syncthreads();
#pragma unroll
  for (int yy = 0; yy < 4; ++yy)
    out[(size_t)(bx * 32 + y + yy * 8) * 1024 + by * 32 + x] = t[x][y + yy * 8];
}

// cvec[r] = sum_h Km[r,h]*bq[h]
__global__ __launch_bounds__(256) void matvec_bias(
    const float* __restrict__ Km, const float* __restrict__ bq, float* __restrict__ cvec)
{
  const int row = blockIdx.x * 4 + (threadIdx.x >> 6);
  const int lane = threadIdx.x & 63;
  float acc = 0.f;
#pragma unroll
  for (int j = 0; j < 16; ++j)
    acc = fmaf(Km[(size_t)row * HDIM + lane + j * 64], bq[lane + j * 64], acc);
#pragma unroll
  for (int off = 32; off; off >>= 1) acc += __shfl_xor(acc, off);
  if (lane == 0) cvec[row] = acc;
}

__global__ __launch_bounds__(256) void f32_to_bf16_k(const float* __restrict__ in, u16* __restrict__ out, long n4) {
  for (long i = blockIdx.x * 256 + threadIdx.x; i < n4; i += (long)gridDim.x * 256) {
    const float4 f = *reinterpret_cast<const float4*>(in + i * 4);
    u16 o[4] = {f2bf(f.x), f2bf(f.y), f2bf(f.z), f2bf(f.w)};
    *reinterpret_cast<ulong1*>(out + i * 4) = *reinterpret_cast<ulong1*>(o);
  }
}

// W2 [2016][1024] f32 -> [2048][1024] bf16 with zero pad rows
__global__ __launch_bounds__(256) void w2_to_bf16_pad(const float* __restrict__ in, u16* __restrict__ out) {
  const long n4 = (long)NPAD * HDIM / 4;
  for (long i = blockIdx.x * 256 + threadIdx.x; i < n4; i += (long)gridDim.x * 256) {
    const long r = i / (HDIM / 4);
    u16 o[4] = {0, 0, 0, 0};
    if (r < R_REL) {
      const float4 f = *reinterpret_cast<const float4*>(in + i * 4);
      o[0] = f2bf(f.x); o[1] = f2bf(f.y); o[2] = f2bf(f.z); o[3] = f2bf(f.w);
    }
    *reinterpret_cast<ulong1*>(out + i * 4) = *reinterpret_cast<ulong1*>(o);
  }
}

// ---------------- fused: prefilter top-32 (approx) -> exact f32 rescore -> top-28 + softmax
__global__ __launch_bounds__(64) void topk_rescore(
    const u16* __restrict__ St, const unsigned long long* __restrict__ fbits,
    const int* __restrict__ f_i, const int* __restrict__ f_j,
    const float* __restrict__ qh, const float* __restrict__ W2, const float* __restrict__ cvec,
    int* __restrict__ topidx, float* __restrict__ topw)
{
  const int gm = blockIdx.x;
  const int lane = threadIdx.x;
  const unsigned long long fb = fbits[gm];

  float val[32];
#pragma unroll
  for (int j = 0; j < 32; ++j) {
    const int rr = lane + j * 64;
    float v = -INFINITY;
    if (rr < R_REL) {
      const int fi = f_i[rr], fj = f_j[rr];
      if (((fb >> fi) & 1ULL) && ((fb >> fj) & 1ULL))
        v = bf2f(St[(size_t)gm * NPAD + rr]);
    }
    val[j] = v;
  }

  // prefilter: top-32 approx candidates (lane c holds candidate index candR)
  int candR = 0x7fffffff;
  int ncand = 0;
  for (int it = 0; it < NCAND; ++it) {
    float bv = -INFINITY; int bi = 0x7fffffff;
#pragma unroll
    for (int j = 0; j < 32; ++j)
      if (val[j] > bv) { bv = val[j]; bi = lane + j * 64; }
#pragma unroll
    for (int off = 32; off; off >>= 1) {
      const float ov = __shfl_xor(bv, off);
      const int oi = __shfl_xor(bi, off);
      if (ov > bv || (ov == bv && oi < bi)) { bv = ov; bi = oi; }
    }
    if (bv == -INFINITY) break;
    if (lane == it) candR = bi;
    ncand = it + 1;
    const int cj = bi >> 6, cl = bi & 63;
#pragma unroll
    for (int j = 0; j < 32; ++j)
      if (j == cj && lane == cl) val[j] = -INFINITY;
  }

  // exact rescore in f32: s = (qh[gm]·W2[r] + cvec[r]) / 32
  float q[16];
  {
    const float* qp = qh + (size_t)gm * HDIM + lane * 16;
#pragma unroll
    for (int v4 = 0; v4 < 4; ++v4) {
      const float4 f = *reinterpret_cast<const float4*>(qp + v4 * 4);
      q[v4 * 4 + 0] = f.x; q[v4 * 4 + 1] = f.y; q[v4 * 4 + 2] = f.z; q[v4 * 4 + 3] = f.w;
    }
  }
  float myscore = -INFINITY;
  for (int c = 0; c < NCAND; ++c) {
    if (c >= ncand) break;
    const int r = __shfl(candR, c);
    const float* wp = W2 + (size_t)r * HDIM + lane * 16;
    float d = 0.f;
#pragma unroll
    for (int v4 = 0; v4 < 4; ++v4) {
      const float4 f = *reinterpret_cast<const float4*>(wp + v4 * 4);
      d = fmaf(q[v4 * 4 + 0], f.x, d);
      d = fmaf(q[v4 * 4 + 1], f.y, d);
      d = fmaf(q[v4 * 4 + 2], f.z, d);
      d = fmaf(q[v4 * 4 + 3], f.w, d);
    }
#pragma unroll
    for (int off = 32; off; off >>= 1) d += __shfl_xor(d, off);
    const float s = (d + cvec[r]) * 0.03125f;
    if (lane == c) myscore = s;
  }

  // exact top-28 among candidates (tie -> lowest index)
  const int myr = candR;
  float outv = 0.f; int outi = 0; float m0 = 0.f; int nsel = 0;
  for (int it = 0; it < TOPK; ++it) {
    float bv = myscore; int br = myr;
#pragma unroll
    for (int off = 32; off; off >>= 1) {
      const float ov = __shfl_xor(bv, off);
      const int orr = __shfl_xor(br, off);
      if (ov > bv || (ov == bv && orr < br)) { bv = ov; br = orr; }
    }
    if (bv == -INFINITY) break;
    if (it == 0) m0 = bv;
    if (lane == it) { outv = bv; outi = br; }
    nsel = it + 1;
    if (myscore == bv && myr == br) myscore = -INFINITY;
  }

  const float e = (lane < nsel) ? expf(outv - m0) : 0.f;
  float z = e;
#pragma unroll
  for (int off = 32; off; off >>= 1) z += __shfl_xor(z, off);
  if (lane < TOPK) {
    topw[(size_t)gm * TOPK + lane] = (lane < nsel) ? (e / z) : 0.f;
    topidx[(size_t)gm * TOPK + lane] = (lane < nsel) ? outi : 0;
  }
}

__global__ __launch_bounds__(256) void out_gather(
    const int* __restrict__ topidx, const float* __restrict__ topw,
    const float* __restrict__ V, float* __restrict__ out)
{
  const int gm = blockIdx.x;
  const int tid = threadIdx.x;
  __shared__ float w[TOPK];
  __shared__ int   id[TOPK];
  if (tid < TOPK) {
    w[tid] = topw[(size_t)gm * TOPK + tid];
    id[tid] = topidx[(size_t)gm * TOPK + tid];
  }
  __syncthreads();
  float4 acc = make_float4(0.f, 0.f, 0.f, 0.f);
#pragma unroll 4
  for (int i = 0; i < TOPK; ++i) {
    const float wi = w[i];
    const float4 v = *reinterpret_cast<const float4*>(V + (size_t)id[i] * HDIM + tid * 4);
    acc.x = fmaf(wi, v.x, acc.x);
    acc.y = fmaf(wi, v.y, acc.y);
    acc.z = fmaf(wi, v.z, acc.z);
    acc.w = fmaf(wi, v.w, acc.w);
  }
  *reinterpret_cast<float4*>(out + (size_t)gm * HDIM + tid * 4) = acc;
}

extern "C" void kernel_launch(void* const* d_in, const int* in_sizes, int n_in,
                              void* d_out, int out_size, void* d_ws, size_t ws_size,
                              hipStream_t stream) {
  const float* qh  = (const float*)d_in[0];
  const void*  mask = d_in[1];
  const float* rel = (const float*)d_in[2];
  const int* f_i = (const int*)d_in[3];
  const int* f_j = (const int*)d_in[4];
  const float* Wt = (const float*)d_in[5]; const float* bt = (const float*)d_in[6];
  const float* Wq = (const float*)d_in[7]; const float* bq = (const float*)d_in[8];
  const float* Wk = (const float*)d_in[9]; const float* bk = (const float*)d_in[10];
  const float* Wv = (const float*)d_in[11]; const float* bv = (const float*)d_in[12];
  float* out = (float*)d_out;

  // workspace layout (bytes)
  char* p = (char*)d_ws;
  float* ta   = (float*)p; p += (size_t)R_REL * HDIM * 4;
  float* Km   = (float*)p; p += (size_t)R_REL * HDIM * 4;
  float* Vm   = (float*)p; p += (size_t)R_REL * HDIM * 4;
  float* W2   = (float*)p; p += (size_t)R_REL * HDIM * 4;
  float* WqT  = (float*)p; p += (size_t)HDIM * HDIM * 4;
  float* cvec = (float*)p; p += (size_t)NPAD * 4;
  unsigned long long* fbits = (unsigned long long*)p; p += (size_t)MROWS * 8;
  int* kindflag = (int*)p; p += 16;
  int* tidx = (int*)p;   p += (size_t)MROWS * TOPK * 4;
  float* tw = (float*)p; p += (size_t)MROWS * TOPK * 4;
  u16* qhb  = (u16*)p;   p += (size_t)MROWS * HDIM * 2;
  u16* W2b  = (u16*)p;   p += (size_t)NPAD * HDIM * 2;
  u16* St   = (u16*)p;   p += (size_t)MROWS * NPAD * 2;

  const dim3 blk(256);
  auto grid_of = [](int m, int n, int z) {
    return dim3((unsigned)((n + 127) / 128), (unsigned)((m + 127) / 128), (unsigned)z);
  };

  detect_mask_kind<<<1, 64, 0, stream>>>((const unsigned int*)mask, kindflag);
  build_fbits<<<dim3(MROWS / 4), blk, 0, stream>>>(mask, kindflag, fbits);
  transpose1024<<<dim3(32, 32), blk, 0, stream>>>(Wq, WqT);

  // ta = rel @ Wt^T + bt
  gemm_nt_f32<<<grid_of(R_REL, HDIM, 1), blk, 0, stream>>>(
      rel, Wt, bt, ta, Wt, bt, ta, R_REL, HDIM, EDIM, 1.f);
  // Km = ta @ Wk^T + bk ; Vm = ta @ Wv^T + bv   (z-batched)
  gemm_nt_f32<<<grid_of(R_REL, HDIM, 2), blk, 0, stream>>>(
      ta, Wk, bk, Km, Wv, bv, Vm, R_REL, HDIM, HDIM, 1.f);
  // W2 = Km @ Wq  (== Km @ WqT^T)
  gemm_nt_f32<<<grid_of(R_REL, HDIM, 1), blk, 0, stream>>>(
      Km, WqT, nullptr, W2, WqT, nullptr, W2, R_REL, HDIM, HDIM, 1.f);
  // cvec = Km @ bq
  matvec_bias<<<dim3(R_REL / 4), blk, 0, stream>>>(Km, bq, cvec);

  // bf16 copies for the MFMA prefilter
  f32_to_bf16_k<<<dim3(2048), blk, 0, stream>>>(qh, qhb, (long)MROWS * HDIM / 4);
  w2_to_bf16_pad<<<dim3(1024), blk, 0, stream>>>(W2, W2b);

  // approx scores St = bf16((qhb @ W2b^T + cvec)/32)
  gemm_bf16_scores<<<dim3(NPAD / 128, MROWS / 128), blk, 0, stream>>>(qhb, W2b, cvec, St, HDIM);

  // prefilter + exact rescore + top-28 + softmax
  topk_rescore<<<dim3(MROWS), dim3(64), 0, stream>>>(St, fbits, f_i, f_j, qh, W2, cvec, tidx, tw);

  out_gather<<<dim3(MROWS), blk, 0, stream>>>(tidx, tw, Vm, out);
}

// Round 4
// 701.624 us; speedup vs baseline: 3.6583x; 1.4788x over previous
//
#include <hip/hip_runtime.h>
#include <hip/hip_bf16.h>

#define R_REL 2016
#define MROWS 16384
#define HDIM  1024
#define EDIM  768
#define TOPK  28
#define KSEL  32
#define CAP   64
#define NPAD  2048

typedef unsigned short u16;
typedef __attribute__((ext_vector_type(8))) short short8;
typedef __attribute__((ext_vector_type(4))) float f32x4;

__device__ inline u16 f2bf(float f) {
  __hip_bfloat16 h = __float2bfloat16(f);
  u16 u; __builtin_memcpy(&u, &h, 2); return u;
}
__device__ inline void gl2lds16(const void* g, void* l) {
  __builtin_amdgcn_global_load_lds((const __attribute__((address_space(1))) unsigned int*)g,
                                   (__attribute__((address_space(3))) unsigned int*)l, 16, 0, 0);
}

// ---------------- f32 NT GEMM, 64x64 tile (small-M GEMMs: >=512 blocks, 2/CU) -----------
__global__ __launch_bounds__(256) void gemm_nt_f32_64(
    const float* __restrict__ A, const float* __restrict__ B,
    const float* __restrict__ bias, float* __restrict__ C,
    int M, int N, int K, float scale)
{
  __shared__ float As[16][68];
  __shared__ float Bs[16][68];
  const int tid = threadIdx.x;
  const int tx = tid & 15, ty = tid >> 4;
  const int r0 = blockIdx.y * 64, c0 = blockIdx.x * 64;

  float acc[4][4];
#pragma unroll
  for (int i = 0; i < 4; ++i)
#pragma unroll
    for (int j = 0; j < 4; ++j) acc[i][j] = 0.f;

  for (int k0 = 0; k0 < K; k0 += 16) {
    {
      const int row = tid >> 2, kv = tid & 3;
      int gr = r0 + row; gr = (gr < M) ? gr : (M - 1);
      const float4 fa = *reinterpret_cast<const float4*>(A + (size_t)gr * K + k0 + kv * 4);
      As[kv * 4 + 0][row] = fa.x; As[kv * 4 + 1][row] = fa.y;
      As[kv * 4 + 2][row] = fa.z; As[kv * 4 + 3][row] = fa.w;
      int gc = c0 + row; gc = (gc < N) ? gc : (N - 1);
      const float4 fb = *reinterpret_cast<const float4*>(B + (size_t)gc * K + k0 + kv * 4);
      Bs[kv * 4 + 0][row] = fb.x; Bs[kv * 4 + 1][row] = fb.y;
      Bs[kv * 4 + 2][row] = fb.z; Bs[kv * 4 + 3][row] = fb.w;
    }
    __syncthreads();
#pragma unroll
    for (int kk = 0; kk < 16; ++kk) {
      const float4 a4 = *reinterpret_cast<const float4*>(&As[kk][ty * 4]);
      const float4 b4 = *reinterpret_cast<const float4*>(&Bs[kk][tx * 4]);
      const float a[4] = {a4.x, a4.y, a4.z, a4.w};
      const float b[4] = {b4.x, b4.y, b4.z, b4.w};
#pragma unroll
      for (int i = 0; i < 4; ++i)
#pragma unroll
        for (int j = 0; j < 4; ++j)
          acc[i][j] = fmaf(a[i], b[j], acc[i][j]);
    }
    __syncthreads();
  }
#pragma unroll
  for (int i = 0; i < 4; ++i) {
    const int r = r0 + ty * 4 + i;
    if (r >= M) continue;
#pragma unroll
    for (int j = 0; j < 4; ++j) {
      const int c = c0 + tx * 4 + j;
      if (c >= N) continue;
      float v = acc[i][j] * scale;
      if (bias) v += bias[c];
      C[(size_t)r * N + c] = v;
    }
  }
}

// ---------------- bf16 MFMA NT GEMM (128x128, BK=32, verified frag mapping) -------------
// MODE 0: Cf[rg*Nstride+cg] = acc + extra[cg]           (Vm)
// MODE 1: Cu[rg*Nstride+cg] = u16key((acc+extra[cg])/32) (scores -> monotone keys)
template<int MODE>
__global__ __launch_bounds__(256) void mfma_nt_bf16(
    const u16* __restrict__ A, const u16* __restrict__ B,
    const float* __restrict__ extra, float* __restrict__ Cf, u16* __restrict__ Cu,
    int K, int Nstride, int Mlim, int Nlim)
{
  __shared__ u16 ldsA[128 * 32];
  __shared__ u16 ldsB[128 * 32];
  const int tid = threadIdx.x;
  const int wave = tid >> 6, lane = tid & 63;
  const int wr = wave >> 1, wc = wave & 1;
  const int row0 = blockIdx.y * 128, col0 = blockIdx.x * 128;

  f32x4 acc[4][4];
#pragma unroll
  for (int m = 0; m < 4; ++m)
#pragma unroll
    for (int n = 0; n < 4; ++n) acc[m][n] = (f32x4){0.f, 0.f, 0.f, 0.f};

  const int srow = (lane >> 2);
  const int sslot = lane & 3;

  for (int k0 = 0; k0 < K; k0 += 32) {
#pragma unroll
    for (int j = 0; j < 2; ++j) {
      const int row = (wave * 2 + j) * 16 + srow;
      const int s = (row >> 1) & 3;
      const int kg = sslot ^ s;
      gl2lds16((const char*)A + ((size_t)(row0 + row) * K + k0 + kg * 8) * 2,
               (char*)ldsA + (size_t)(wave * 2 + j) * 1024);
      gl2lds16((const char*)B + ((size_t)(col0 + row) * K + k0 + kg * 8) * 2,
               (char*)ldsB + (size_t)(wave * 2 + j) * 1024);
    }
    __syncthreads();
    const int r15 = lane & 15, kq = lane >> 4;
    short8 a[4], b[4];
#pragma unroll
    for (int m = 0; m < 4; ++m) {
      const int rowL = wr * 64 + m * 16 + r15;
      const int slot = kq ^ ((rowL >> 1) & 3);
      a[m] = *reinterpret_cast<const short8*>(&ldsA[rowL * 32 + slot * 8]);
    }
#pragma unroll
    for (int n = 0; n < 4; ++n) {
      const int colL = wc * 64 + n * 16 + r15;
      const int slot = kq ^ ((colL >> 1) & 3);
      b[n] = *reinterpret_cast<const short8*>(&ldsB[colL * 32 + slot * 8]);
    }
#pragma unroll
    for (int m = 0; m < 4; ++m)
#pragma unroll
      for (int n = 0; n < 4; ++n)
        acc[m][n] = __builtin_amdgcn_mfma_f32_16x16x32_bf16(a[m], b[n], acc[m][n], 0, 0, 0);
    __syncthreads();
  }
  const int r15 = lane & 15, quad = lane >> 4;
#pragma unroll
  for (int m = 0; m < 4; ++m)
#pragma unroll
    for (int n = 0; n < 4; ++n) {
      const int cg = col0 + wc * 64 + n * 16 + r15;
      if (cg >= Nlim) continue;
      const float ev = extra ? extra[cg] : 0.f;
#pragma unroll
      for (int reg = 0; reg < 4; ++reg) {
        const int rg = row0 + wr * 64 + m * 16 + quad * 4 + reg;
        if (rg >= Mlim) continue;
        const float v = acc[m][n][reg] + ev;
        if constexpr (MODE == 0) {
          Cf[(size_t)rg * Nstride + cg] = v;
        } else {
          const float s = v * 0.03125f;
          const u16 u = f2bf(s);
          const u16 key = (u & 0x8000) ? (u16)(~u) : (u16)(u | 0x8000);
          Cu[(size_t)rg * Nstride + cg] = key;
        }
      }
    }
}

// ---------------- small helpers ----------------
__global__ void detect_mask_kind(const unsigned int* __restrict__ m, int* __restrict__ flag) {
  if (threadIdx.x == 0 && blockIdx.x == 0) {
    int kind = 0; bool saw_gt1 = false;
    for (int i = 0; i < 256; ++i) {
      unsigned w = m[i];
      if (w == 0x3F800000u) { kind = 2; saw_gt1 = false; break; }
      if (w > 1u) saw_gt1 = true;
    }
    if (kind != 2 && saw_gt1) kind = 1;
    *flag = kind;
  }
}

__global__ __launch_bounds__(256) void build_fbits(
    const void* __restrict__ mask, const int* __restrict__ kind,
    unsigned long long* __restrict__ fbits)
{
  const int gm = blockIdx.x * 4 + (threadIdx.x >> 6);
  const int lane = threadIdx.x & 63;
  const int k = *kind;
  const size_t e = (size_t)gm * 64 + lane;
  bool on;
  if (k == 0)      on = ((const int*)mask)[e] != 0;
  else if (k == 1) on = ((const unsigned char*)mask)[e] != 0;
  else             on = ((const float*)mask)[e] != 0.f;
  const unsigned long long b = __ballot(on);
  if (lane == 0) fbits[gm] = b;
}

__global__ __launch_bounds__(256) void transpose1024(const float* __restrict__ in, float* __restrict__ out) {
  __shared__ float t[32][33];
  const int x = threadIdx.x & 31, y = threadIdx.x >> 5;
  const int bx = blockIdx.x, by = blockIdx.y;
#pragma unroll
  for (int yy = 0; yy < 4; ++yy)
    t[y + yy * 8][x] = in[(size_t)(by * 32 + y + yy * 8) * 1024 + bx * 32 + x];
  __syncthreads();
#pragma unroll
  for (int yy = 0; yy < 4; ++yy)
    out[(size_t)(bx * 32 + y + yy * 8) * 1024 + by * 32 + x] = t[x][y + yy * 8];
}

__global__ __launch_bounds__(256) void matvec_bias(
    const float* __restrict__ Km, const float* __restrict__ bq, float* __restrict__ cvec)
{
  const int row = blockIdx.x * 4 + (threadIdx.x >> 6);
  const int lane = threadIdx.x & 63;
  float acc = 0.f;
#pragma unroll
  for (int j = 0; j < 16; ++j)
    acc = fmaf(Km[(size_t)row * HDIM + lane + j * 64], bq[lane + j * 64], acc);
#pragma unroll
  for (int off = 32; off; off >>= 1) acc += __shfl_xor(acc, off);
  if (lane == 0) cvec[row] = acc;
}

// f32 -> bf16, flat, zero-pad beyond n4_valid (valid region is leading & contiguous)
__global__ __launch_bounds__(256) void conv_bf16_pad(
    const float* __restrict__ in, u16* __restrict__ out, long n4_total, long n4_valid)
{
  for (long i = blockIdx.x * 256 + threadIdx.x; i < n4_total; i += (long)gridDim.x * 256) {
    u16 o[4] = {0, 0, 0, 0};
    if (i < n4_valid) {
      const float4 f = *reinterpret_cast<const float4*>(in + i * 4);
      o[0] = f2bf(f.x); o[1] = f2bf(f.y); o[2] = f2bf(f.z); o[3] = f2bf(f.w);
    }
    *reinterpret_cast<ulong1*>(out + i * 4) = *reinterpret_cast<ulong1*>(o);
  }
}

__global__ void fij_pack_k(const int* __restrict__ f_i, const int* __restrict__ f_j,
                           unsigned* __restrict__ fij) {
  const int i = blockIdx.x * 256 + threadIdx.x;
  if (i < NPAD) {
    const int src = (i < R_REL) ? i : (R_REL - 1);
    fij[i] = ((unsigned)f_i[src] & 0xFFFFu) | (((unsigned)f_j[src] & 0xFFFFu) << 16);
  }
}

// ---------------- radix-select prefilter + exact f32 rescore + bitonic top-28 + softmax --
__global__ __launch_bounds__(64) void topk_radix(
    const u16* __restrict__ Kt, const unsigned long long* __restrict__ fbits,
    const unsigned* __restrict__ fij,
    const float* __restrict__ qh, const float* __restrict__ W2, const float* __restrict__ cvec,
    int* __restrict__ topidx, float* __restrict__ topw)
{
  const int gm = blockIdx.x;
  const int lane = threadIdx.x;
  const unsigned long long fb = fbits[gm];
  __shared__ int cand[CAP];

  // load 32 keys (lane's rr set: lane*8 + r + L*512), mask inactive/pad -> key 0
  unsigned key[32];
  const u16* rowp = Kt + (size_t)gm * NPAD;
#pragma unroll
  for (int L = 0; L < 4; ++L) {
    const int rrb = lane * 8 + L * 512;
    const short8 v = *reinterpret_cast<const short8*>(rowp + rrb);
    const uint4 p0 = *reinterpret_cast<const uint4*>(fij + rrb);
    const uint4 p1 = *reinterpret_cast<const uint4*>(fij + rrb + 4);
    const unsigned ps[8] = {p0.x, p0.y, p0.z, p0.w, p1.x, p1.y, p1.z, p1.w};
#pragma unroll
    for (int r = 0; r < 8; ++r) {
      const int rr = rrb + r;
      const unsigned p = ps[r];
      const bool act = (rr < R_REL) &&
        ((((fb >> (p & 63u)) & (fb >> (p >> 16))) & 1ULL) != 0);
      key[L * 8 + r] = act ? (unsigned)(u16)v[r] : 0u;
    }
  }

  // binary search largest T in [1,65535] with count(key >= T) >= KSEL (16 iters, SALU counts)
  int lo = 1, hi = 65536;
  while (hi - lo > 1) {
    const int mid = (lo + hi) >> 1;
    int cnt = 0;
#pragma unroll
    for (int j = 0; j < 32; ++j)
      cnt += __popcll(__ballot(key[j] >= (unsigned)mid));
    if (cnt >= KSEL) lo = mid; else hi = mid;
  }
  const unsigned T = (unsigned)lo;

  // extract candidates (deterministic (j,lane) order), capped at CAP
  int base = 0;
#pragma unroll
  for (int L = 0; L < 4; ++L) {
#pragma unroll
    for (int r = 0; r < 8; ++r) {
      const int j = L * 8 + r;
      const bool c = key[j] >= T;
      const unsigned long long m = __ballot(c);
      const unsigned mlo = (unsigned)m;
      const unsigned mhi = (unsigned)(m >> 32);
      const int pre = __builtin_amdgcn_mbcnt_hi(mhi, __builtin_amdgcn_mbcnt_lo(mlo, 0));
      const int slot = base + pre;
      if (c && slot < CAP) cand[slot] = lane * 8 + r + L * 512;
      base += __popcll(m);
    }
  }
  const int ncand = (base < CAP) ? base : CAP;
  __syncthreads();

  // exact f32 rescore: s = (qh[gm]·W2[r] + cvec[r]) / 32
  float q[16];
  {
    const float* qp = qh + (size_t)gm * HDIM + lane * 16;
#pragma unroll
    for (int v4 = 0; v4 < 4; ++v4) {
      const float4 f = *reinterpret_cast<const float4*>(qp + v4 * 4);
      q[v4 * 4 + 0] = f.x; q[v4 * 4 + 1] = f.y; q[v4 * 4 + 2] = f.z; q[v4 * 4 + 3] = f.w;
    }
  }
  float myscore = -INFINITY;
  int myr = 0x7fffffff;
  for (int c = 0; c < CAP; ++c) {
    if (c >= ncand) break;
    const int r = cand[c];
    const float* wp = W2 + (size_t)r * HDIM + lane * 16;
    float d = 0.f;
#pragma unroll
    for (int v4 = 0; v4 < 4; ++v4) {
      const float4 f = *reinterpret_cast<const float4*>(wp + v4 * 4);
      d = fmaf(q[v4 * 4 + 0], f.x, d);
      d = fmaf(q[v4 * 4 + 1], f.y, d);
      d = fmaf(q[v4 * 4 + 2], f.z, d);
      d = fmaf(q[v4 * 4 + 3], f.w, d);
    }
#pragma unroll
    for (int off = 32; off; off >>= 1) d += __shfl_xor(d, off);
    const float s = (d + cvec[r]) * 0.03125f;
    if (lane == c) myscore = s;
  }
  if (lane < ncand) myr = cand[lane];

  // bitonic sort 64 lanes, descending score, tie -> ascending index (matches top_k)
#pragma unroll
  for (int k = 2; k <= 64; k <<= 1) {
#pragma unroll
    for (int j = k >> 1; j > 0; j >>= 1) {
      const float ov = __shfl_xor(myscore, j);
      const int oi = __shfl_xor(myr, j);
      const bool lower = (lane & j) == 0;
      const bool want_desc = (lane & k) == 0;
      const bool mine_better = (myscore > ov) || (myscore == ov && myr < oi);
      const bool keep = (lower == want_desc) ? mine_better : !mine_better;
      if (!keep) { myscore = ov; myr = oi; }
    }
  }

  const int nvalid = __popcll(__ballot(myscore > -INFINITY));
  const int nsel = (nvalid < TOPK) ? nvalid : TOPK;
  const float m0 = __shfl(myscore, 0);
  const float e = (lane < nsel) ? expf(myscore - m0) : 0.f;
  float z = e;
#pragma unroll
  for (int off = 32; off; off >>= 1) z += __shfl_xor(z, off);
  if (lane < TOPK) {
    topw[(size_t)gm * TOPK + lane] = (lane < nsel) ? (e / z) : 0.f;
    topidx[(size_t)gm * TOPK + lane] = (lane < nsel) ? myr : 0;
  }
}

__global__ __launch_bounds__(256) void out_gather(
    const int* __restrict__ topidx, const float* __restrict__ topw,
    const float* __restrict__ V, float* __restrict__ out)
{
  const int gm = blockIdx.x;
  const int tid = threadIdx.x;
  __shared__ float w[TOPK];
  __shared__ int   id[TOPK];
  if (tid < TOPK) {
    w[tid] = topw[(size_t)gm * TOPK + tid];
    id[tid] = topidx[(size_t)gm * TOPK + tid];
  }
  __syncthreads();
  float4 acc = make_float4(0.f, 0.f, 0.f, 0.f);
#pragma unroll 4
  for (int i = 0; i < TOPK; ++i) {
    const float wi = w[i];
    const float4 v = *reinterpret_cast<const float4*>(V + (size_t)id[i] * HDIM + tid * 4);
    acc.x = fmaf(wi, v.x, acc.x);
    acc.y = fmaf(wi, v.y, acc.y);
    acc.z = fmaf(wi, v.z, acc.z);
    acc.w = fmaf(wi, v.w, acc.w);
  }
  *reinterpret_cast<float4*>(out + (size_t)gm * HDIM + tid * 4) = acc;
}

extern "C" void kernel_launch(void* const* d_in, const int* in_sizes, int n_in,
                              void* d_out, int out_size, void* d_ws, size_t ws_size,
                              hipStream_t stream) {
  const float* qh  = (const float*)d_in[0];
  const void*  mask = d_in[1];
  const float* rel = (const float*)d_in[2];
  const int* f_i = (const int*)d_in[3];
  const int* f_j = (const int*)d_in[4];
  const float* Wt = (const float*)d_in[5]; const float* bt = (const float*)d_in[6];
  const float* Wq = (const float*)d_in[7]; const float* bq = (const float*)d_in[8];
  const float* Wk = (const float*)d_in[9]; const float* bk = (const float*)d_in[10];
  const float* Wv = (const float*)d_in[11]; const float* bv = (const float*)d_in[12];
  float* out = (float*)d_out;

  char* p = (char*)d_ws;
  float* ta   = (float*)p; p += (size_t)R_REL * HDIM * 4;
  float* Km   = (float*)p; p += (size_t)R_REL * HDIM * 4;
  float* Vm   = (float*)p; p += (size_t)R_REL * HDIM * 4;
  float* W2   = (float*)p; p += (size_t)R_REL * HDIM * 4;
  float* WqT  = (float*)p; p += (size_t)HDIM * HDIM * 4;
  u16* ta16   = (u16*)p;   p += (size_t)NPAD * HDIM * 2;
  u16* Wv16   = (u16*)p;   p += (size_t)HDIM * HDIM * 2;
  u16* qhb    = (u16*)p;   p += (size_t)MROWS * HDIM * 2;
  u16* W2b    = (u16*)p;   p += (size_t)NPAD * HDIM * 2;
  u16* Kt     = (u16*)p;   p += (size_t)MROWS * NPAD * 2;
  float* cvec = (float*)p; p += (size_t)NPAD * 4;
  unsigned long long* fbits = (unsigned long long*)p; p += (size_t)MROWS * 8;
  unsigned* fij = (unsigned*)p; p += (size_t)NPAD * 4;
  int* kindflag = (int*)p; p += 16;
  int* tidx = (int*)p;   p += (size_t)MROWS * TOPK * 4;
  float* tw = (float*)p; p += (size_t)MROWS * TOPK * 4;

  const dim3 blk(256);

  detect_mask_kind<<<1, 64, 0, stream>>>((const unsigned int*)mask, kindflag);
  build_fbits<<<dim3(MROWS / 4), blk, 0, stream>>>(mask, kindflag, fbits);
  fij_pack_k<<<dim3(NPAD / 256), blk, 0, stream>>>(f_i, f_j, fij);
  transpose1024<<<dim3(32, 32), blk, 0, stream>>>(Wq, WqT);

  // K-chain (exact f32): ta = rel@Wt^T+bt ; Km = ta@Wk^T+bk ; W2 = Km@WqT^T
  gemm_nt_f32_64<<<dim3(HDIM / 64, (R_REL + 63) / 64), blk, 0, stream>>>(
      rel, Wt, bt, ta, R_REL, HDIM, EDIM, 1.f);
  gemm_nt_f32_64<<<dim3(HDIM / 64, (R_REL + 63) / 64), blk, 0, stream>>>(
      ta, Wk, bk, Km, R_REL, HDIM, HDIM, 1.f);
  gemm_nt_f32_64<<<dim3(HDIM / 64, (R_REL + 63) / 64), blk, 0, stream>>>(
      Km, WqT, nullptr, W2, R_REL, HDIM, HDIM, 1.f);
  matvec_bias<<<dim3(R_REL / 4), blk, 0, stream>>>(Km, bq, cvec);

  // Vm via bf16 MFMA (precision budget ample): ta16, Wv16 -> Vm = ta@Wv^T + bv
  conv_bf16_pad<<<dim3(512), blk, 0, stream>>>(ta, ta16, (long)NPAD * HDIM / 4, (long)R_REL * HDIM / 4);
  conv_bf16_pad<<<dim3(512), blk, 0, stream>>>(Wv, Wv16, (long)HDIM * HDIM / 4, (long)HDIM * HDIM / 4);
  mfma_nt_bf16<0><<<dim3(HDIM / 128, NPAD / 128), blk, 0, stream>>>(
      ta16, Wv16, bv, Vm, nullptr, HDIM, HDIM, R_REL, HDIM);

  // approx score keys: Kt = key((qhb @ W2b^T + cvec)/32)
  conv_bf16_pad<<<dim3(2048), blk, 0, stream>>>(qh, qhb, (long)MROWS * HDIM / 4, (long)MROWS * HDIM / 4);
  conv_bf16_pad<<<dim3(512), blk, 0, stream>>>(W2, W2b, (long)NPAD * HDIM / 4, (long)R_REL * HDIM / 4);
  mfma_nt_bf16<1><<<dim3(NPAD / 128, MROWS / 128), blk, 0, stream>>>(
      qhb, W2b, cvec, nullptr, Kt, HDIM, NPAD, MROWS, R_REL);

  // radix prefilter + exact rescore + top-28 + softmax
  topk_radix<<<dim3(MROWS), dim3(64), 0, stream>>>(Kt, fbits, fij, qh, W2, cvec, tidx, tw);

  out_gather<<<dim3(MROWS), blk, 0, stream>>>(tidx, tw, Vm, out);
}